// Round 5
// baseline (1647.926 us; speedup 1.0000x reference)
//
#include <hip/hip_runtime.h>
#include <hip/hip_cooperative_groups.h>
#include <stdint.h>

namespace cg = cooperative_groups;

#define NPIX 786432
#define KNB 9
#define CIN 16
#define COUT 16
#define NPAIR 8                      // CIN/2
#define WPAIRS (COUT * KNB * NPAIR)  // 1152

typedef _Float16 half2_t __attribute__((ext_vector_type(2)));
typedef uint32_t u32x4 __attribute__((ext_vector_type(4)));
typedef float    f32x4 __attribute__((ext_vector_type(4)));

__device__ __forceinline__ uint32_t packf16(float lo, float hi) {
    half2_t h;
    h[0] = (_Float16)lo;   // RNE convert
    h[1] = (_Float16)hi;
    return __builtin_bit_cast(uint32_t, h);
}
__device__ __forceinline__ half2_t ash2(uint32_t v) {
    return __builtin_bit_cast(half2_t, v);
}

// One k-step: 16 output channels x 8 f16-pair dots against row (q0,q1).
__device__ __forceinline__ void conv_step(
    int k, u32x4 q0, u32x4 q1, const uint32_t* __restrict__ w2, float* acc)
{
    const uint32_t xp[NPAIR] = {q0[0], q0[1], q0[2], q0[3],
                                q1[0], q1[1], q1[2], q1[3]};
    const uint32_t* __restrict__ wk = w2 + k * NPAIR;  // w2[o*72 + k*8 + j]
#pragma unroll
    for (int o = 0; o < COUT; ++o) {
        const uint32_t* __restrict__ wo = wk + o * (KNB * NPAIR);
        float a = acc[o];
#pragma unroll
        for (int j = 0; j < NPAIR; ++j)
            a = __builtin_amdgcn_fdot2(ash2(xp[j]), ash2(wo[j]), a, false);
        acc[o] = a;
    }
}

__device__ __forceinline__ void pack_pixel(
    const float* __restrict__ x, uint32_t* __restrict__ xw, int p)
{
    uint32_t v[16];
    if (p < NPIX) {
        const f32x4* __restrict__ r0 = (const f32x4*)(x + (size_t)p * CIN);
        const f32x4* __restrict__ r1 =
            (const f32x4*)(x + (size_t)NPIX * CIN + (size_t)p * CIN);
        const f32x4 a0 = __builtin_nontemporal_load(r0 + 0);
        const f32x4 a1 = __builtin_nontemporal_load(r0 + 1);
        const f32x4 a2 = __builtin_nontemporal_load(r0 + 2);
        const f32x4 a3 = __builtin_nontemporal_load(r0 + 3);
        const f32x4 b0 = __builtin_nontemporal_load(r1 + 0);
        const f32x4 b1 = __builtin_nontemporal_load(r1 + 1);
        const f32x4 b2 = __builtin_nontemporal_load(r1 + 2);
        const f32x4 b3 = __builtin_nontemporal_load(r1 + 3);
        v[0]  = packf16(a0[0], a0[1]); v[1]  = packf16(a0[2], a0[3]);
        v[2]  = packf16(a1[0], a1[1]); v[3]  = packf16(a1[2], a1[3]);
        v[4]  = packf16(a2[0], a2[1]); v[5]  = packf16(a2[2], a2[3]);
        v[6]  = packf16(a3[0], a3[1]); v[7]  = packf16(a3[2], a3[3]);
        v[8]  = packf16(b0[0], b0[1]); v[9]  = packf16(b0[2], b0[3]);
        v[10] = packf16(b1[0], b1[1]); v[11] = packf16(b1[2], b1[3]);
        v[12] = packf16(b2[0], b2[1]); v[13] = packf16(b2[2], b2[3]);
        v[14] = packf16(b3[0], b3[1]); v[15] = packf16(b3[2], b3[3]);
    } else {
#pragma unroll
        for (int i = 0; i < 16; ++i) v[i] = 0u;  // pad row = zeros
    }
    u32x4* __restrict__ o = (u32x4*)(xw + (size_t)p * 16);
    o[0] = (u32x4){v[0],  v[1],  v[2],  v[3]};
    o[1] = (u32x4){v[4],  v[5],  v[6],  v[7]};
    o[2] = (u32x4){v[8],  v[9],  v[10], v[11]};
    o[3] = (u32x4){v[12], v[13], v[14], v[15]};
}

__device__ __forceinline__ void conv_elem(
    const uint32_t* __restrict__ xw, const int* __restrict__ neigh,
    const uint32_t* __restrict__ w2, const float* __restrict__ bias,
    float* __restrict__ out, int t)
{
    const int px = t >> 1;
    const int b  = t & 1;

    int idx[KNB];
#pragma unroll
    for (int k = 0; k < KNB; ++k) {
        int id = neigh[px * KNB + k];
        id = id < 0 ? 0 : (id > NPIX ? NPIX : id);  // defensive clamp
        idx[k] = id;
    }

    const uint32_t* __restrict__ base = xw + b * NPAIR;  // batch half of row

#define ROWPTR(K) ((const u32x4*)(base + (size_t)idx[K] * 16))
    const u32x4 r0a = ROWPTR(0)[0], r0b = ROWPTR(0)[1];
    const u32x4 r1a = ROWPTR(1)[0], r1b = ROWPTR(1)[1];
    const u32x4 r2a = ROWPTR(2)[0], r2b = ROWPTR(2)[1];
    const u32x4 r3a = ROWPTR(3)[0], r3b = ROWPTR(3)[1];
    const u32x4 r4a = ROWPTR(4)[0], r4b = ROWPTR(4)[1];
    const u32x4 r5a = ROWPTR(5)[0], r5b = ROWPTR(5)[1];
    const u32x4 r6a = ROWPTR(6)[0], r6b = ROWPTR(6)[1];
    const u32x4 r7a = ROWPTR(7)[0], r7b = ROWPTR(7)[1];
    const u32x4 r8a = ROWPTR(8)[0], r8b = ROWPTR(8)[1];
#undef ROWPTR
    // NOTE: no forcing barrier here. r0 (sunk, VGPR 36) == r3 (barrier,
    // VGPR 48) == ~150 us: conv is request-rate-bound, not MLP-bound.
    // Under the 64-VGPR cooperative cap a barrier would force spills.

    float acc[COUT];
#pragma unroll
    for (int o = 0; o < COUT; ++o) acc[o] = bias[o];

    conv_step(0, r0a, r0b, w2, acc);
    conv_step(1, r1a, r1b, w2, acc);
    conv_step(2, r2a, r2b, w2, acc);
    conv_step(3, r3a, r3b, w2, acc);
    conv_step(4, r4a, r4b, w2, acc);
    conv_step(5, r5a, r5b, w2, acc);
    conv_step(6, r6a, r6b, w2, acc);
    conv_step(7, r7a, r7b, w2, acc);
    conv_step(8, r8a, r8b, w2, acc);

    float* __restrict__ op = out + (size_t)b * NPIX * COUT + (size_t)px * COUT;
    ((float4*)op)[0] = make_float4(acc[0],  acc[1],  acc[2],  acc[3]);
    ((float4*)op)[1] = make_float4(acc[4],  acc[5],  acc[6],  acc[7]);
    ((float4*)op)[2] = make_float4(acc[8],  acc[9],  acc[10], acc[11]);
    ((float4*)op)[3] = make_float4(acc[12], acc[13], acc[14], acc[15]);
}

// ---------------------------------------------------------------------------
// Fused cooperative kernel: phase A packs x->xw (f16) grid-strided, then a
// grid-wide sync (device-scope fence covers cross-XCD L2 visibility of xw),
// then phase B does the 9-neighbour gather-conv grid-strided.
// 2048 blocks x 256 thr = exactly 8 blocks/CU on 256 CUs;
// __launch_bounds__(256,8) caps VGPRs at 64 so co-residency holds.
// Purpose: collapse pack+conv+inter-kernel gap into ONE dispatch to attack
// the ~184 us constant (total - conv) that pack-side changes never moved.
// ---------------------------------------------------------------------------
__global__ __launch_bounds__(256, 8) void fused_kernel(
    const float* __restrict__ x,
    const int* __restrict__ neigh,
    const float* __restrict__ w,
    const float* __restrict__ bias,
    uint32_t* __restrict__ xw,
    uint32_t* __restrict__ w2,
    float* __restrict__ out)
{
    const int tid    = (int)blockIdx.x * 256 + (int)threadIdx.x;
    const int stride = (int)gridDim.x * 256;

    // ---- Phase A: pack ----
    if (blockIdx.x == 0) {
        for (int j = threadIdx.x; j < WPAIRS; j += 256)
            w2[j] = packf16(w[2 * j], w[2 * j + 1]);
    }
    for (int p = tid; p <= NPIX; p += stride)
        pack_pixel(x, xw, p);

    cg::this_grid().sync();

    // ---- Phase B: conv ----
    for (int t = tid; t < 2 * NPIX; t += stride)
        conv_elem(xw, neigh, w2, bias, out, t);
}

// ---------------- fallback two-kernel path (non-cooperative) ----------------
__global__ __launch_bounds__(256) void pack_kernel(
    const float* __restrict__ x, const float* __restrict__ w,
    uint32_t* __restrict__ xw, uint32_t* __restrict__ w2)
{
    if (blockIdx.x == 0) {
        for (int j = threadIdx.x; j < WPAIRS; j += 256)
            w2[j] = packf16(w[2 * j], w[2 * j + 1]);
    }
    const int stride = (int)gridDim.x * 256;
    for (int p = (int)blockIdx.x * 256 + (int)threadIdx.x; p <= NPIX; p += stride)
        pack_pixel(x, xw, p);
}

__global__ __launch_bounds__(256, 4) void healpix_conv_kernel(
    const uint32_t* __restrict__ xw,
    const int* __restrict__ neigh,
    const uint32_t* __restrict__ w2,
    const float* __restrict__ bias,
    float* __restrict__ out)
{
    const int t = (int)blockIdx.x * 256 + (int)threadIdx.x;
    conv_elem(xw, neigh, w2, bias, out, t);
}

extern "C" void kernel_launch(void* const* d_in, const int* in_sizes, int n_in,
                              void* d_out, int out_size, void* d_ws, size_t ws_size,
                              hipStream_t stream) {
    const float* x     = (const float*)d_in[0];
    const int*   neigh = (const int*)d_in[1];
    const float* w     = (const float*)d_in[2];
    const float* bias  = (const float*)d_in[3];
    float* out = (float*)d_out;

    uint32_t* xw = (uint32_t*)d_ws;                      // (NPIX+1)*16 u32 = 50.3 MB
    uint32_t* w2 = xw + (size_t)(NPIX + 1) * 16;         // 1152 u32

    // Cooperative capacity: query once, cap at 2048 (8 blocks/CU x 256 CU).
    static int nblocks = 0;
    if (nblocks == 0) {
        int occ = 0;
        if (hipOccupancyMaxActiveBlocksPerMultiprocessor(&occ, fused_kernel, 256, 0)
                != hipSuccess || occ < 1)
            occ = 0;
        nblocks = occ * 256;
        if (nblocks > 2048) nblocks = 2048;
        if (nblocks <= 0) nblocks = -1;   // cooperative not viable
    }

    bool ok = false;
    if (nblocks > 0) {
        void* args[] = {(void*)&x, (void*)&neigh, (void*)&w, (void*)&bias,
                        (void*)&xw, (void*)&w2, (void*)&out};
        ok = (hipLaunchCooperativeKernel(fused_kernel, dim3(nblocks), dim3(256),
                                         args, 0, stream) == hipSuccess);
        if (!ok) nblocks = -1;            // don't retry every call
    }
    if (!ok) {
        pack_kernel<<<2048, 256, 0, stream>>>(x, w, xw, w2);
        const int conv_blocks = (2 * NPIX) / 256;        // 6144
        healpix_conv_kernel<<<conv_blocks, 256, 0, stream>>>(xw, neigh, w2, bias, out);
    }
}

// Round 7
// 333.407 us; speedup vs baseline: 4.9427x; 4.9427x over previous
//
#include <hip/hip_runtime.h>
#include <stdint.h>

#define NPIX 786432
#define KNB 9
#define CIN 16
#define COUT 16
#define NPAIR 8                      // CIN/2
#define WPAIRS (COUT * KNB * NPAIR)  // 1152

typedef _Float16 half2_t __attribute__((ext_vector_type(2)));
typedef uint32_t u32x4 __attribute__((ext_vector_type(4)));
typedef float    f32x4 __attribute__((ext_vector_type(4)));

__device__ __forceinline__ uint32_t packf16(float lo, float hi) {
    half2_t h;
    h[0] = (_Float16)lo;   // RNE convert
    h[1] = (_Float16)hi;
    return __builtin_bit_cast(uint32_t, h);
}
__device__ __forceinline__ half2_t ash2(uint32_t v) {
    return __builtin_bit_cast(half2_t, v);
}

// ---------------------------------------------------------------------------
// Pre-pass: x (2, NPIX, 16) fp32 -> xw (NPIX+1, 2, 16) f16 packed as 16 u32
// per pixel (batch0's 8 pairs then batch1's 8 pairs), explicit ZERO row at
// p == NPIX. Block 0 additionally packs w (16,9,16) fp32 -> 1152 u32 pairs.
// Grid-stride, 2048 blocks; x loads nontemporal (read-once stream).
// ~35 us — at its streaming floor (r3 vs r4 pack variants identical).
// ---------------------------------------------------------------------------
__global__ __launch_bounds__(256) void pack_kernel(
    const float* __restrict__ x, const float* __restrict__ w,
    uint32_t* __restrict__ xw, uint32_t* __restrict__ w2)
{
    if (blockIdx.x == 0) {
        for (int j = threadIdx.x; j < WPAIRS; j += 256)
            w2[j] = packf16(w[2 * j], w[2 * j + 1]);
    }

    const int stride = (int)gridDim.x * 256;
    for (int p = (int)blockIdx.x * 256 + (int)threadIdx.x; p <= NPIX; p += stride) {
        uint32_t v[16];
        if (p < NPIX) {
            const f32x4* __restrict__ r0 = (const f32x4*)(x + (size_t)p * CIN);
            const f32x4* __restrict__ r1 =
                (const f32x4*)(x + (size_t)NPIX * CIN + (size_t)p * CIN);
            const f32x4 a0 = __builtin_nontemporal_load(r0 + 0);
            const f32x4 a1 = __builtin_nontemporal_load(r0 + 1);
            const f32x4 a2 = __builtin_nontemporal_load(r0 + 2);
            const f32x4 a3 = __builtin_nontemporal_load(r0 + 3);
            const f32x4 b0 = __builtin_nontemporal_load(r1 + 0);
            const f32x4 b1 = __builtin_nontemporal_load(r1 + 1);
            const f32x4 b2 = __builtin_nontemporal_load(r1 + 2);
            const f32x4 b3 = __builtin_nontemporal_load(r1 + 3);
            v[0]  = packf16(a0[0], a0[1]); v[1]  = packf16(a0[2], a0[3]);
            v[2]  = packf16(a1[0], a1[1]); v[3]  = packf16(a1[2], a1[3]);
            v[4]  = packf16(a2[0], a2[1]); v[5]  = packf16(a2[2], a2[3]);
            v[6]  = packf16(a3[0], a3[1]); v[7]  = packf16(a3[2], a3[3]);
            v[8]  = packf16(b0[0], b0[1]); v[9]  = packf16(b0[2], b0[3]);
            v[10] = packf16(b1[0], b1[1]); v[11] = packf16(b1[2], b1[3]);
            v[12] = packf16(b2[0], b2[1]); v[13] = packf16(b2[2], b2[3]);
            v[14] = packf16(b3[0], b3[1]); v[15] = packf16(b3[2], b3[3]);
        } else {
#pragma unroll
            for (int i = 0; i < 16; ++i) v[i] = 0u;  // pad row = zeros
        }

        u32x4* __restrict__ o = (u32x4*)(xw + (size_t)p * 16);
        o[0] = (u32x4){v[0],  v[1],  v[2],  v[3]};
        o[1] = (u32x4){v[4],  v[5],  v[6],  v[7]};
        o[2] = (u32x4){v[8],  v[9],  v[10], v[11]};
        o[3] = (u32x4){v[12], v[13], v[14], v[15]};
    }
}

// One k-step: 16 output channels x 8 f16-pair dots against row (q0,q1).
__device__ __forceinline__ void conv_step(
    int k, u32x4 q0, u32x4 q1, const uint32_t* __restrict__ w2, float* acc)
{
    const uint32_t xp[NPAIR] = {q0[0], q0[1], q0[2], q0[3],
                                q1[0], q1[1], q1[2], q1[3]};
    const uint32_t* __restrict__ wk = w2 + k * NPAIR;  // w2[o*72 + k*8 + j]
#pragma unroll
    for (int o = 0; o < COUT; ++o) {
        const uint32_t* __restrict__ wo = wk + o * (KNB * NPAIR);
        float a = acc[o];
#pragma unroll
        for (int j = 0; j < NPAIR; ++j)
            a = __builtin_amdgcn_fdot2(ash2(xp[j]), ash2(wo[j]), a, false);
        acc[o] = a;
    }
}

// ---------------------------------------------------------------------------
// Main: one thread per (pixel, batch). Lane pairs (2i,2i+1) share a pixel ->
// their 32 B halves of the same 64 B row coalesce; the two 64 B halves of a
// 128 B xw row are fetched back-to-back (full byte utilization, consecutive
// lines at the DRAM). ~150 us = 3.6 TB/s random-64B-granule fabric ceiling:
// invariant across sunk-load / value-pin / memory-clobber / occupancy 46-55%
// regimes (r0/r2/r3/r4). FETCH = logical minimum (9*NPIX*64 B).
// ---------------------------------------------------------------------------
__global__ __launch_bounds__(256, 4) void healpix_conv_kernel(
    const uint32_t* __restrict__ xw,
    const int* __restrict__ neigh,
    const uint32_t* __restrict__ w2,
    const float* __restrict__ bias,
    float* __restrict__ out)
{
    const int t  = blockIdx.x * 256 + threadIdx.x;  // [0, 2*NPIX)
    const int px = t >> 1;
    const int b  = t & 1;

    int idx[KNB];
#pragma unroll
    for (int k = 0; k < KNB; ++k) {
        int id = neigh[px * KNB + k];
        id = id < 0 ? 0 : (id > NPIX ? NPIX : id);  // defensive clamp
        idx[k] = id;
    }

    const uint32_t* __restrict__ base = xw + b * NPAIR;  // batch half of row

#define ROWPTR(K) ((const u32x4*)(base + (size_t)idx[K] * 16))
    const u32x4 r0a = ROWPTR(0)[0], r0b = ROWPTR(0)[1];
    const u32x4 r1a = ROWPTR(1)[0], r1b = ROWPTR(1)[1];
    const u32x4 r2a = ROWPTR(2)[0], r2b = ROWPTR(2)[1];
    const u32x4 r3a = ROWPTR(3)[0], r3b = ROWPTR(3)[1];
    const u32x4 r4a = ROWPTR(4)[0], r4b = ROWPTR(4)[1];
    const u32x4 r5a = ROWPTR(5)[0], r5b = ROWPTR(5)[1];
    const u32x4 r6a = ROWPTR(6)[0], r6b = ROWPTR(6)[1];
    const u32x4 r7a = ROWPTR(7)[0], r7b = ROWPTR(7)[1];
    const u32x4 r8a = ROWPTR(8)[0], r8b = ROWPTR(8)[1];
#undef ROWPTR

    // Memory-clobber barrier: loads above may not sink past a may-write asm,
    // and may not be rematerialized below it.
    asm volatile("" ::: "memory");

    float acc[COUT];
#pragma unroll
    for (int o = 0; o < COUT; ++o) acc[o] = bias[o];

    conv_step(0, r0a, r0b, w2, acc);
    conv_step(1, r1a, r1b, w2, acc);
    conv_step(2, r2a, r2b, w2, acc);
    conv_step(3, r3a, r3b, w2, acc);
    conv_step(4, r4a, r4b, w2, acc);
    conv_step(5, r5a, r5b, w2, acc);
    conv_step(6, r6a, r6b, w2, acc);
    conv_step(7, r7a, r7b, w2, acc);
    conv_step(8, r8a, r8b, w2, acc);

    float* __restrict__ op = out + (size_t)b * NPIX * COUT + (size_t)px * COUT;
    ((float4*)op)[0] = make_float4(acc[0],  acc[1],  acc[2],  acc[3]);
    ((float4*)op)[1] = make_float4(acc[4],  acc[5],  acc[6],  acc[7]);
    ((float4*)op)[2] = make_float4(acc[8],  acc[9],  acc[10], acc[11]);
    ((float4*)op)[3] = make_float4(acc[12], acc[13], acc[14], acc[15]);
}

extern "C" void kernel_launch(void* const* d_in, const int* in_sizes, int n_in,
                              void* d_out, int out_size, void* d_ws, size_t ws_size,
                              hipStream_t stream) {
    const float* x     = (const float*)d_in[0];
    const int*   neigh = (const int*)d_in[1];
    const float* w     = (const float*)d_in[2];
    const float* bias  = (const float*)d_in[3];
    float* out = (float*)d_out;

    uint32_t* xw = (uint32_t*)d_ws;                      // (NPIX+1)*16 u32 = 50.3 MB
    uint32_t* w2 = xw + (size_t)(NPIX + 1) * 16;         // 1152 u32

    pack_kernel<<<2048, 256, 0, stream>>>(x, w, xw, w2);

    const int conv_blocks = (2 * NPIX) / 256;            // 6144
    healpix_conv_kernel<<<conv_blocks, 256, 0, stream>>>(xw, neigh, w2, bias, out);
}

// Round 8
// 321.786 us; speedup vs baseline: 5.1212x; 1.0361x over previous
//
#include <hip/hip_runtime.h>
#include <stdint.h>

#define NPIX 786432
#define KNB 9
#define CIN 16
#define COUT 16
#define NPAIR 8                      // CIN/2
#define WPAIRS (COUT * KNB * NPAIR)  // 1152

typedef _Float16 half2_t __attribute__((ext_vector_type(2)));
typedef uint32_t u32x4 __attribute__((ext_vector_type(4)));
typedef float    f32x4 __attribute__((ext_vector_type(4)));

__device__ __forceinline__ uint32_t packf16(float lo, float hi) {
    half2_t h;
    h[0] = (_Float16)lo;   // RNE convert
    h[1] = (_Float16)hi;
    return __builtin_bit_cast(uint32_t, h);
}
__device__ __forceinline__ half2_t ash2(uint32_t v) {
    return __builtin_bit_cast(half2_t, v);
}

// ---------------------------------------------------------------------------
// Pre-pass, FULLY-COALESCED form: one thread per 16 B output chunk of
// xw (NPIX+1, 2, 16) f16. Chunk T covers xw u32s [4T, 4T+4):
//   p = T>>2, q = T&3, b = q>>1, j = q&1
//   out pairs jj = j*4 .. j*4+3  <=>  x floats [b][p][8j .. 8j+8)  (32 B in)
// A wave's loads form two contiguous 1 KB segments (one per batch region);
// stores are one contiguous 1 KB segment. This removes the stride-64
// partial-line pattern of the thread-per-pixel pack (the H1 suspect for
// pack running ~6x off its streaming roofline). Conv is byte-identical.
// ---------------------------------------------------------------------------
__global__ __launch_bounds__(256) void pack_kernel(
    const float* __restrict__ x, const float* __restrict__ w,
    uint32_t* __restrict__ xw, uint32_t* __restrict__ w2)
{
    if (blockIdx.x == 0) {
        for (int j = threadIdx.x; j < WPAIRS; j += 256)
            w2[j] = packf16(w[2 * j], w[2 * j + 1]);
    }

    const int nchunk = (NPIX + 1) * 4;        // 3,145,732 16B-chunks
    const int stride = (int)gridDim.x * 256;
    for (int T = (int)blockIdx.x * 256 + (int)threadIdx.x; T < nchunk; T += stride) {
        const int p = T >> 2;
        const int q = T & 3;
        const int b = q >> 1;
        const int j = q & 1;

        u32x4 v;
        if (p < NPIX) {
            const f32x4* __restrict__ src = (const f32x4*)(
                x + (size_t)b * NPIX * CIN + (size_t)p * CIN + j * 8);
            const f32x4 s0 = __builtin_nontemporal_load(src + 0);
            const f32x4 s1 = __builtin_nontemporal_load(src + 1);
            v[0] = packf16(s0[0], s0[1]);
            v[1] = packf16(s0[2], s0[3]);
            v[2] = packf16(s1[0], s1[1]);
            v[3] = packf16(s1[2], s1[3]);
        } else {
            v = (u32x4){0u, 0u, 0u, 0u};      // pad row = zeros
        }
        ((u32x4*)xw)[T] = v;                  // regular store: conv wants xw cached
    }
}

// One k-step: 16 output channels x 8 f16-pair dots against row (q0,q1).
__device__ __forceinline__ void conv_step(
    int k, u32x4 q0, u32x4 q1, const uint32_t* __restrict__ w2, float* acc)
{
    const uint32_t xp[NPAIR] = {q0[0], q0[1], q0[2], q0[3],
                                q1[0], q1[1], q1[2], q1[3]};
    const uint32_t* __restrict__ wk = w2 + k * NPAIR;  // w2[o*72 + k*8 + j]
#pragma unroll
    for (int o = 0; o < COUT; ++o) {
        const uint32_t* __restrict__ wo = wk + o * (KNB * NPAIR);
        float a = acc[o];
#pragma unroll
        for (int j = 0; j < NPAIR; ++j)
            a = __builtin_amdgcn_fdot2(ash2(xp[j]), ash2(wo[j]), a, false);
        acc[o] = a;
    }
}

// ---------------------------------------------------------------------------
// Main: one thread per (pixel, batch). Lane pairs (2i,2i+1) share a pixel ->
// their 32 B halves of the same 64 B row coalesce. ~150 us = 3.6 TB/s
// random-64B-granule fabric ceiling: invariant across sunk-load / value-pin /
// memory-clobber / occupancy 46-55% regimes (r0/r2/r3/r4/r7). FETCH =
// logical minimum (9*NPIX*64 B). BYTE-IDENTICAL to round 7.
// ---------------------------------------------------------------------------
__global__ __launch_bounds__(256, 4) void healpix_conv_kernel(
    const uint32_t* __restrict__ xw,
    const int* __restrict__ neigh,
    const uint32_t* __restrict__ w2,
    const float* __restrict__ bias,
    float* __restrict__ out)
{
    const int t  = blockIdx.x * 256 + threadIdx.x;  // [0, 2*NPIX)
    const int px = t >> 1;
    const int b  = t & 1;

    int idx[KNB];
#pragma unroll
    for (int k = 0; k < KNB; ++k) {
        int id = neigh[px * KNB + k];
        id = id < 0 ? 0 : (id > NPIX ? NPIX : id);  // defensive clamp
        idx[k] = id;
    }

    const uint32_t* __restrict__ base = xw + b * NPAIR;  // batch half of row

#define ROWPTR(K) ((const u32x4*)(base + (size_t)idx[K] * 16))
    const u32x4 r0a = ROWPTR(0)[0], r0b = ROWPTR(0)[1];
    const u32x4 r1a = ROWPTR(1)[0], r1b = ROWPTR(1)[1];
    const u32x4 r2a = ROWPTR(2)[0], r2b = ROWPTR(2)[1];
    const u32x4 r3a = ROWPTR(3)[0], r3b = ROWPTR(3)[1];
    const u32x4 r4a = ROWPTR(4)[0], r4b = ROWPTR(4)[1];
    const u32x4 r5a = ROWPTR(5)[0], r5b = ROWPTR(5)[1];
    const u32x4 r6a = ROWPTR(6)[0], r6b = ROWPTR(6)[1];
    const u32x4 r7a = ROWPTR(7)[0], r7b = ROWPTR(7)[1];
    const u32x4 r8a = ROWPTR(8)[0], r8b = ROWPTR(8)[1];
#undef ROWPTR

    // Memory-clobber barrier: loads above may not sink past a may-write asm,
    // and may not be rematerialized below it.
    asm volatile("" ::: "memory");

    float acc[COUT];
#pragma unroll
    for (int o = 0; o < COUT; ++o) acc[o] = bias[o];

    conv_step(0, r0a, r0b, w2, acc);
    conv_step(1, r1a, r1b, w2, acc);
    conv_step(2, r2a, r2b, w2, acc);
    conv_step(3, r3a, r3b, w2, acc);
    conv_step(4, r4a, r4b, w2, acc);
    conv_step(5, r5a, r5b, w2, acc);
    conv_step(6, r6a, r6b, w2, acc);
    conv_step(7, r7a, r7b, w2, acc);
    conv_step(8, r8a, r8b, w2, acc);

    float* __restrict__ op = out + (size_t)b * NPIX * COUT + (size_t)px * COUT;
    ((float4*)op)[0] = make_float4(acc[0],  acc[1],  acc[2],  acc[3]);
    ((float4*)op)[1] = make_float4(acc[4],  acc[5],  acc[6],  acc[7]);
    ((float4*)op)[2] = make_float4(acc[8],  acc[9],  acc[10], acc[11]);
    ((float4*)op)[3] = make_float4(acc[12], acc[13], acc[14], acc[15]);
}

extern "C" void kernel_launch(void* const* d_in, const int* in_sizes, int n_in,
                              void* d_out, int out_size, void* d_ws, size_t ws_size,
                              hipStream_t stream) {
    const float* x     = (const float*)d_in[0];
    const int*   neigh = (const int*)d_in[1];
    const float* w     = (const float*)d_in[2];
    const float* bias  = (const float*)d_in[3];
    float* out = (float*)d_out;

    uint32_t* xw = (uint32_t*)d_ws;                      // (NPIX+1)*16 u32 = 50.3 MB
    uint32_t* w2 = xw + (size_t)(NPIX + 1) * 16;         // 1152 u32

    pack_kernel<<<2048, 256, 0, stream>>>(x, w, xw, w2);

    const int conv_blocks = (2 * NPIX) / 256;            // 6144
    healpix_conv_kernel<<<conv_blocks, 256, 0, stream>>>(xw, neigh, w2, bias, out);
}